// Round 4
// baseline (267.663 us; speedup 1.0000x reference)
//
#include <hip/hip_runtime.h>

// PseudoImageScatter: (4,12000,64) fp32 features + (4,12000,4) int coords
// -> (4,64,496,496) fp32 grid, last-write-wins on duplicate (y,x).
//
// Pass 0: hipMemsetAsync winner map to 0xFF (-1 per int) — graph-capturable.
// Pass 1: winner[b][y][x] = atomicMax of pillar index (numpy last-write-wins).
// Pass 2: gather, one thread per int4 of winner cells: read winner once,
//         stream each winning pillar's 256 B feature row via float4 loads,
//         register-transpose, emit 64 coalesced NONTEMPORAL 16 B stores
//         (output has zero reuse — keep it out of L2 so winner/feat stay
//         resident). Traffic: 252 MB stores (mandatory) + ~16 MB reads.
//
// NOTE: __builtin_nontemporal_store requires a NATIVE vector type — HIP's
// float4 (HIP_vector_type struct) is rejected. Use ext_vector_type(4).

typedef float vf4 __attribute__((ext_vector_type(4)));

constexpr int B = 4, P = 12000, Fdim = 64, H = 496, W = 496;
constexpr int W4 = W / 4;                 // 124 vf4 per row
constexpr int NCELL = B * H * W;          // 984064 -> 3.94 MB winner map in d_ws
constexpr int NPILLAR = B * P;            // 48000
constexpr int PLANE4 = H * W4;            // 61504 vf4 per (b,f) plane
constexpr int NG4 = NCELL / 4;            // 246016; 64 | PLANE4 so waves
                                          // never straddle a batch edge

__global__ void scatter_winner_kernel(const int4* __restrict__ coords,
                                      int* __restrict__ winner) {
    int i = blockIdx.x * blockDim.x + threadIdx.x;
    if (i >= NPILLAR) return;
    int b = i / P;
    int p = i - b * P;
    int4 c = coords[i];                   // [?, y, x, ?] — one 16 B load
    int y = c.y;
    int x = c.z;
    // invalid coords land in the sliced-off column of the reference -> skip
    if ((unsigned)y < (unsigned)H && (unsigned)x < (unsigned)W)
        atomicMax(&winner[(b * H + y) * W + x], p);
}

__global__ void __launch_bounds__(256)
gather_kernel(const float* __restrict__ feat,
              const int* __restrict__ winner,
              vf4* __restrict__ out) {
    int g = blockIdx.x * blockDim.x + threadIdx.x;
    if (g >= NG4) return;

    int4 w = reinterpret_cast<const int4*>(winner)[g];

    int b = g / PLANE4;
    int r = g - b * PLANE4;                 // y*W4 + x4 within the plane
    vf4* op = out + (size_t)b * Fdim * PLANE4 + r;

    // clamped base pointers are always in-bounds; loads are exec-masked below
    const vf4* p0 = reinterpret_cast<const vf4*>(feat + ((size_t)b * P + max(w.x, 0)) * Fdim);
    const vf4* p1 = reinterpret_cast<const vf4*>(feat + ((size_t)b * P + max(w.y, 0)) * Fdim);
    const vf4* p2 = reinterpret_cast<const vf4*>(feat + ((size_t)b * P + max(w.z, 0)) * Fdim);
    const vf4* p3 = reinterpret_cast<const vf4*>(feat + ((size_t)b * P + max(w.w, 0)) * Fdim);
    const vf4 z4 = (vf4)0.f;

#pragma unroll
    for (int c = 0; c < Fdim / 4; ++c) {    // 16 chunks of 4 channels
        vf4 a0 = z4, a1 = z4, a2 = z4, a3 = z4;
        if (w.x >= 0) a0 = p0[c];
        if (w.y >= 0) a1 = p1[c];
        if (w.z >= 0) a2 = p2[c];
        if (w.w >= 0) a3 = p3[c];
        // register transpose: channel f = 4c+j takes component j of each cell
        vf4 o0 = {a0.x, a1.x, a2.x, a3.x};
        vf4 o1 = {a0.y, a1.y, a2.y, a3.y};
        vf4 o2 = {a0.z, a1.z, a2.z, a3.z};
        vf4 o3 = {a0.w, a1.w, a2.w, a3.w};
        __builtin_nontemporal_store(o0, op + (4 * c + 0) * PLANE4);
        __builtin_nontemporal_store(o1, op + (4 * c + 1) * PLANE4);
        __builtin_nontemporal_store(o2, op + (4 * c + 2) * PLANE4);
        __builtin_nontemporal_store(o3, op + (4 * c + 3) * PLANE4);
    }
}

extern "C" void kernel_launch(void* const* d_in, const int* in_sizes, int n_in,
                              void* d_out, int out_size, void* d_ws, size_t ws_size,
                              hipStream_t stream) {
    const float* feat  = (const float*)d_in[0];
    const int4* coords = (const int4*)d_in[1];  // integer inputs arrive as int32
    int* winner        = (int*)d_ws;            // 3.94 MB scratch

    // 0xFF bytes == -1 as int32: "empty" marker
    (void)hipMemsetAsync(winner, 0xFF, (size_t)NCELL * sizeof(int), stream);
    scatter_winner_kernel<<<(NPILLAR + 255) / 256, 256, 0, stream>>>(coords, winner);
    gather_kernel<<<(NG4 + 255) / 256, 256, 0, stream>>>(feat, winner, (vf4*)d_out);
}

// Round 5
// 261.441 us; speedup vs baseline: 1.0238x; 1.0238x over previous
//
#include <hip/hip_runtime.h>

// PseudoImageScatter: (4,12000,64) fp32 features + (4,12000,4) int coords
// -> (4,64,496,496) fp32 grid, last-write-wins on duplicate (y,x).
//
// Pass 0: hipMemsetAsync winner map to 0xFF (-1 per int) — graph-capturable.
// Pass 1: winner[b][y][x] = atomicMax of pillar index (numpy last-write-wins).
// Pass 2: gather, one thread per int4 of winner cells: read winner once,
//         stream each winning pillar's 256 B feature row via float4 loads,
//         register-transpose, emit 64 coalesced 16 B stores (one per channel
//         plane; lanes consecutive in x4 -> full 1 KB/instr wave stores).
//         Traffic: 252 MB stores (mandatory) + ~16 MB reads.
//
// Round-4 lesson: nontemporal stores were neutral-to-negative (267.7 vs
// 260.4 µs) — the plain store stream already self-evicts through L2 without
// hurting the small read set. Reverted to plain vector stores.

typedef float vf4 __attribute__((ext_vector_type(4)));

constexpr int B = 4, P = 12000, Fdim = 64, H = 496, W = 496;
constexpr int W4 = W / 4;                 // 124 vf4 per row
constexpr int NCELL = B * H * W;          // 984064 -> 3.94 MB winner map in d_ws
constexpr int NPILLAR = B * P;            // 48000
constexpr int PLANE4 = H * W4;            // 61504 vf4 per (b,f) plane
constexpr int NG4 = NCELL / 4;            // 246016; 64 | PLANE4 so waves
                                          // never straddle a batch edge

__global__ void scatter_winner_kernel(const int4* __restrict__ coords,
                                      int* __restrict__ winner) {
    int i = blockIdx.x * blockDim.x + threadIdx.x;
    if (i >= NPILLAR) return;
    int b = i / P;
    int p = i - b * P;
    int4 c = coords[i];                   // [?, y, x, ?] — one 16 B load
    int y = c.y;
    int x = c.z;
    // invalid coords land in the sliced-off column of the reference -> skip
    if ((unsigned)y < (unsigned)H && (unsigned)x < (unsigned)W)
        atomicMax(&winner[(b * H + y) * W + x], p);
}

__global__ void __launch_bounds__(256)
gather_kernel(const float* __restrict__ feat,
              const int* __restrict__ winner,
              vf4* __restrict__ out) {
    int g = blockIdx.x * blockDim.x + threadIdx.x;
    if (g >= NG4) return;

    int4 w = reinterpret_cast<const int4*>(winner)[g];

    int b = g / PLANE4;
    int r = g - b * PLANE4;                 // y*W4 + x4 within the plane
    vf4* op = out + (size_t)b * Fdim * PLANE4 + r;

    // clamped base pointers are always in-bounds; loads are exec-masked below
    const vf4* p0 = reinterpret_cast<const vf4*>(feat + ((size_t)b * P + max(w.x, 0)) * Fdim);
    const vf4* p1 = reinterpret_cast<const vf4*>(feat + ((size_t)b * P + max(w.y, 0)) * Fdim);
    const vf4* p2 = reinterpret_cast<const vf4*>(feat + ((size_t)b * P + max(w.z, 0)) * Fdim);
    const vf4* p3 = reinterpret_cast<const vf4*>(feat + ((size_t)b * P + max(w.w, 0)) * Fdim);
    const vf4 z4 = (vf4)0.f;

#pragma unroll
    for (int c = 0; c < Fdim / 4; ++c) {    // 16 chunks of 4 channels
        vf4 a0 = z4, a1 = z4, a2 = z4, a3 = z4;
        if (w.x >= 0) a0 = p0[c];
        if (w.y >= 0) a1 = p1[c];
        if (w.z >= 0) a2 = p2[c];
        if (w.w >= 0) a3 = p3[c];
        // register transpose: channel f = 4c+j takes component j of each cell
        op[(4 * c + 0) * PLANE4] = vf4{a0.x, a1.x, a2.x, a3.x};
        op[(4 * c + 1) * PLANE4] = vf4{a0.y, a1.y, a2.y, a3.y};
        op[(4 * c + 2) * PLANE4] = vf4{a0.z, a1.z, a2.z, a3.z};
        op[(4 * c + 3) * PLANE4] = vf4{a0.w, a1.w, a2.w, a3.w};
    }
}

extern "C" void kernel_launch(void* const* d_in, const int* in_sizes, int n_in,
                              void* d_out, int out_size, void* d_ws, size_t ws_size,
                              hipStream_t stream) {
    const float* feat  = (const float*)d_in[0];
    const int4* coords = (const int4*)d_in[1];  // integer inputs arrive as int32
    int* winner        = (int*)d_ws;            // 3.94 MB scratch

    // 0xFF bytes == -1 as int32: "empty" marker
    (void)hipMemsetAsync(winner, 0xFF, (size_t)NCELL * sizeof(int), stream);
    scatter_winner_kernel<<<(NPILLAR + 255) / 256, 256, 0, stream>>>(coords, winner);
    gather_kernel<<<(NG4 + 255) / 256, 256, 0, stream>>>(feat, winner, (vf4*)d_out);
}